// Round 17
// baseline (4861.085 us; speedup 1.0000x reference)
//
#include <hip/hip_runtime.h>
#include <cmath>

#define SEQ  256
#define BATCH 128
#define FEAT 512
#define HID  1024
#define G4   4096
#define BH (BATCH*HID)

typedef __attribute__((ext_vector_type(8))) _Float16 f16x8;
typedef __attribute__((ext_vector_type(4))) float f32x4;
typedef __attribute__((ext_vector_type(4))) unsigned u32x4;

__device__ __forceinline__ unsigned short f16_rne(float f) {
  _Float16 h = (_Float16)f;
  return __builtin_bit_cast(unsigned short, h);
}
__device__ __forceinline__ float f16_tof(unsigned short s) {
  return (float)__builtin_bit_cast(_Float16, s);
}
__device__ __forceinline__ void gload16(const unsigned short* g, unsigned short* l) {
  __builtin_amdgcn_global_load_lds(
      (const __attribute__((address_space(1))) unsigned int*)g,
      (__attribute__((address_space(3))) unsigned int*)l, 16, 0, 0);
}
__device__ __forceinline__ float sigf(float x) { return 1.f/(1.f+expf(-x)); }

// ---- sc0/sc1 (L3-coherence-point) slab primitives — R10-validated ----
__device__ __forceinline__ void st1u(unsigned* p, unsigned v) {
  asm volatile("global_store_dword %0, %1, off sc0 sc1" :: "v"(p), "v"(v) : "memory");
}
__device__ __forceinline__ u32x4 ld4u(const unsigned* p) {
  u32x4 r;
  asm volatile("global_load_dwordx4 %0, %1, off sc0 sc1" : "=v"(r) : "v"(p) : "memory");
  return r;
}
__device__ __forceinline__ unsigned ld1u(const unsigned* p) {
  unsigned r;
  asm volatile("global_load_dword %0, %1, off sc0 sc1" : "=v"(r) : "v"(p) : "memory");
  return r;
}
__device__ __forceinline__ void wait0() {
  asm volatile("s_waitcnt vmcnt(0)" ::: "memory");
  __builtin_amdgcn_sched_barrier(0);      // rule #18
}
__device__ __forceinline__ unsigned ldcnt(unsigned* p) {
  return __hip_atomic_load(p, __ATOMIC_RELAXED, __HIP_MEMORY_SCOPE_SYSTEM);
}
__device__ __forceinline__ void bump(unsigned* p) {
  __hip_atomic_fetch_add(p, 1u, __ATOMIC_RELAXED, __HIP_MEMORY_SCOPE_SYSTEM);
}

// ---------------- one-time conversion kernels ----------------

__global__ __launch_bounds__(256)
void conv16(const float* __restrict__ src, unsigned short* __restrict__ dst, int n4) {
  for (int i = blockIdx.x*256 + threadIdx.x; i < n4; i += gridDim.x*256) {
    const float4 v = ((const float4*)src)[i];
    ushort4 h;
    h.x = f16_rne(v.x); h.y = f16_rne(v.y); h.z = f16_rne(v.z); h.w = f16_rne(v.w);
    ((ushort4*)dst)[i] = h;
  }
}

// WoutT[c][k] = f16(Wout[k][c])
__global__ __launch_bounds__(256)
void transp16(const float* __restrict__ src, unsigned short* __restrict__ dst) {
  const int i = blockIdx.x*256 + threadIdx.x;   // 1M
  const int k = i >> 10, c = i & 1023;
  dst[(c << 10) + k] = f16_rne(src[i]);
}

// f32 -> f16 with gate-row permutation: r = g*1024+n -> prow = n*4+g
__global__ __launch_bounds__(256)
void conv_perm16(const float* __restrict__ src, unsigned short* __restrict__ dst,
                 int n4, int ksh) {
  for (int i = blockIdx.x*256 + threadIdx.x; i < n4; i += gridDim.x*256) {
    const float4 v = ((const float4*)src)[i];
    const int row = i >> ksh, cq = i & ((1 << ksh) - 1);
    const int prow = ((row & 1023) << 2) | (row >> 10);
    ushort4 h;
    h.x = f16_rne(v.x); h.y = f16_rne(v.y); h.z = f16_rne(v.z); h.w = f16_rne(v.w);
    ((ushort4*)dst)[(prow << ksh) + cq] = h;
  }
}

// bperm[l][prow] = bih + bhh (gate-permuted, f32)
__global__ __launch_bounds__(256)
void bias_perm(const float* __restrict__ bih, const float* __restrict__ bhh,
               float* __restrict__ bperm) {
  const int i = blockIdx.x*256 + threadIdx.x;
  if (i >= 3*G4) return;
  const int l = i >> 12, r = i & 4095;
  const int prow = ((r & 1023) << 2) | (r >> 10);
  bperm[(l << 12) + prow] = bih[i] + bhh[i];
}

// dst[prow(r)] += W[r,:] . b   (f32 weights, gate-permuted dest)
__global__ __launch_bounds__(256)
void gemvf(const float* __restrict__ W, const float* __restrict__ b,
           float* __restrict__ dst, int nrows) {
  const int r = blockIdx.x*256 + threadIdx.x;
  if (r >= nrows) return;
  const float4* wr = (const float4*)(W + (size_t)r*HID);
  float acc = 0.f;
  for (int k = 0; k < 256; ++k) {
    const float4 w = wr[k]; const float4 bb = ((const float4*)b)[k];
    acc += w.x*bb.x + w.y*bb.y + w.z*bb.z + w.w*bb.w;
  }
  dst[((r & 1023) << 2) | (r >> 10)] += acc;
}

// ---------------- 1-product fp16 MFMA GEMM core, 3-deep pipeline ----------------
// acc += A @ W^T. 8 waves as WRN x WCN; wave tile (MI*16)x(NI*16);
// BM=128, BN=256, BK=64. Triple-buffered LDS (144 KB) + gload_lds(16B) +
// XOR-(row&7) swizzle; 2 chunks prefetched ahead, counted vmcnt(12).
template<int MI, int NI, int WRN, int WCN>
__device__ __forceinline__ void mm_core(
    unsigned short* lds, int n0, int kstart, int nch,
    const unsigned short* A1, int K1, const unsigned short* A2,
    const unsigned short* W1, const unsigned short* W2,
    f32x4 acc[MI][NI])
{
  constexpr int AROWS = WRN*MI*16;          // 128
  constexpr int WROWS = WCN*NI*16;          // 256
  constexpr int OW  = AROWS*64;
  constexpr int STRIDE = (AROWS + WROWS)*64;  // 24576 ushorts
  constexpr int NLD = (AROWS + WROWS)/64;   // 6
  const int tid = threadIdx.x;
  const int lane = tid & 63, wave = tid >> 6;
  const int wr = wave / WCN, wc = wave % WCN;
  const int rl = lane >> 3, cc = lane & 7;
  const int gcol = (cc ^ rl) << 3;

  auto stage = [&](int ch) {
    const int kg = kstart + (ch << 6);
    const unsigned short *pA, *pW; int sA, sW;
    if (kg < K1) { pA = A1 + kg; sA = K1;   pW = W1 + kg; sW = K1; }
    else { const int k2 = kg - K1; pA = A2 + k2; sA = 1024; pW = W2 + k2; sW = 1024; }
    unsigned short* const db = lds + (ch % 3)*STRIDE;
    #pragma unroll
    for (int q = 0; q < NLD; ++q) {
      const int g = wave*NLD + q;
      if (g < AROWS/8)
        gload16(pA + (size_t)(g*8 + rl)*sA + gcol, db + g*512);
      else
        gload16(pW + (size_t)(n0 + (g - AROWS/8)*8 + rl)*sW + gcol, db + g*512);
    }
  };

  stage(0);
  stage(1);                                 // nch >= 4 for all roles
  for (int ch = 0; ch < nch; ++ch) {
    if (ch + 2 < nch) {
      stage(ch + 2);
      asm volatile("s_waitcnt vmcnt(12)" ::: "memory");
    } else if (ch + 1 < nch) {
      asm volatile("s_waitcnt vmcnt(6)" ::: "memory");
    } else {
      asm volatile("s_waitcnt vmcnt(0)" ::: "memory");
    }
    __builtin_amdgcn_sched_barrier(0);
    __builtin_amdgcn_s_barrier();
    const unsigned short* const cb = lds + (ch % 3)*STRIDE;
    #pragma unroll
    for (int kh = 0; kh < 2; ++kh) {
      const int j0 = (kh << 2) + (lane >> 4);
      f16x8 ah[MI], bh[NI];
      #pragma unroll
      for (int mi = 0; mi < MI; ++mi) {
        const int row = wr*(MI*16) + (mi << 4) + (lane & 15);
        const int off = row*64 + ((j0 ^ (row & 7)) << 3);
        ah[mi] = *(const f16x8*)(cb + off);
      }
      #pragma unroll
      for (int ni = 0; ni < NI; ++ni) {
        const int wrow = wc*(NI*16) + (ni << 4) + (lane & 15);
        const int off = wrow*64 + ((j0 ^ (wrow & 7)) << 3);
        bh[ni] = *(const f16x8*)(cb + OW + off);
      }
      #pragma unroll
      for (int mi = 0; mi < MI; ++mi)
        #pragma unroll
        for (int ni = 0; ni < NI; ++ni)
          acc[mi][ni] = __builtin_amdgcn_mfma_f32_16x16x32_f16(ah[mi], bh[ni], acc[mi][ni], 0,0,0);
    }
    __builtin_amdgcn_s_barrier();
  }
}

// ---------------- Wfused = Wihr @ Wout -> gate-permuted f16 ----------------
__global__ __launch_bounds__(512, 1)
void wfuse_kernel(const unsigned short* __restrict__ A,
                  const unsigned short* __restrict__ WT,
                  unsigned short* __restrict__ dstP)
{
  __shared__ unsigned short smem[3*(128+256)*64];   // 144 KB
  const int mb = blockIdx.x, jy = blockIdx.y;
  const unsigned short* Ar = A + (size_t)(mb*128)*HID;
  f32x4 z4 = {0.f,0.f,0.f,0.f};
  f32x4 acc[4][4];
  #pragma unroll
  for (int a = 0; a < 4; ++a) { acc[a][0]=z4; acc[a][1]=z4; acc[a][2]=z4; acc[a][3]=z4; }
  mm_core<4,4,2,4>(smem, jy << 8, 0, 16, Ar, HID, Ar, WT, WT, acc);

  const int lane = threadIdx.x & 63, wave = threadIdx.x >> 6;
  const int wr = wave >> 2, wc = wave & 3;
  const int rb = (lane >> 4) << 2, cbl = lane & 15;
  #pragma unroll
  for (int mi = 0; mi < 4; ++mi)
    #pragma unroll
    for (int ni = 0; ni < 4; ++ni)
      #pragma unroll
      for (int r = 0; r < 4; ++r) {
        const int row = mb*128 + (wr << 6) + (mi << 4) + rb + r;
        const int col = (jy << 8) + (wc << 6) + (ni << 4) + cbl;
        dstP[((size_t)(((row & 1023) << 2) | (row >> 10)) << 10) + col] = f16_rne(acc[mi][ni][r]);
      }
}

// ---------------- fused per-diagonal kernel (ONE launch per diag) ----------------
// 240 blocks, 144KB LDS -> 1/CU, all co-resident:
//   [0,64)    gates l=0 (jt 0..15, kz 0..3)  K=1536 = x | h0          (6 chunks)
//   [64,128)  gates l=1                      K=2048 = s0 | h1         (8 chunks)
//   [128,144) ext  l=1 (jtf 0..3, kz 0..3)   K=1024 = s0 @ Wout       (4 chunks)
//   [144,208) gates l=2                      K=2048 = s1 | h2         (8 chunks)
//   [208,224) ext  l=2                       K=1024 = s1 @ Wout       (4 chunks)
//   [224,240) out  (jt 0..3, kz 0..3)        K=1024 = s2 @ Wout       (4 chunks)
// Slabs: f16 row-pair-packed u32, sc0/sc1 both sides; relaxed system tickets.
__global__ __launch_bounds__(512, 1)
void diag_fused(int d,
    const unsigned short* __restrict__ xC,
    unsigned short* __restrict__ hC,   // [2][3][BH]
    unsigned short* __restrict__ sC,   // [2][3][BH]
    const unsigned short* __restrict__ Wih0p, const unsigned short* __restrict__ Whhp,
    const unsigned short* __restrict__ Wf1p,  const unsigned short* __restrict__ Wf2p,
    const unsigned short* __restrict__ WoutC,
    const float* __restrict__ bperm, const float* __restrict__ bout,
    float* __restrict__ cst, unsigned* __restrict__ slabs,
    unsigned* __restrict__ tk, float* __restrict__ out)
{
  __shared__ unsigned short smem[3*(128+256)*64];   // 144 KB
  const int bid = blockIdx.x, tid = threadIdx.x;
  const int p = d & 1, rp = 1 - p;                  // write slot p, read slot rp

  int l, jt, kz, KZ, gid, role;                     // role 0=gates 1=ext 2=out
  if (bid < 64)       { l=0; jt=bid>>2;            kz=bid&3; KZ=4; gid=jt;    role=0; }
  else if (bid < 128) { l=1; int u=bid-64;  jt=u>>2; kz=u&3; KZ=4; gid=16+jt; role=0; }
  else if (bid < 144) { l=1; int w=bid-128; jt=w>>2; kz=w&3; KZ=4; gid=48+jt; role=1; }
  else if (bid < 208) { l=2; int u=bid-144; jt=u>>2; kz=u&3; KZ=4; gid=32+jt; role=0; }
  else if (bid < 224) { l=2; int w=bid-208; jt=w>>2; kz=w&3; KZ=4; gid=52+jt; role=1; }
  else                { l=3; int u=bid-224; jt=u>>2; kz=u&3; KZ=4; gid=56+jt; role=2; }
  const int t = d - ((role==2) ? 3 : l);
  if (t < 0 || t >= SEQ) return;

  // ---- operand selection ----
  const unsigned short *A1_, *A2_, *W1_, *W2_;
  int K1, kstart, nch;
  if (role == 0) {
    if (l == 0) {
      A1_ = xC + (size_t)t*BATCH*FEAT;
      K1 = FEAT; W1_ = Wih0p; kstart = kz*384; nch = 6;
    } else {
      A1_ = sC + ((size_t)rp*3 + (l-1))*BH;
      K1 = HID; W1_ = (l==1) ? Wf1p : Wf2p; kstart = kz*512; nch = 8;
    }
    A2_ = hC + ((size_t)rp*3 + l)*BH;
    W2_ = Whhp + (size_t)l*G4*HID;
  } else if (role == 1) {
    A1_ = sC + ((size_t)rp*3 + (l-1))*BH;
    K1 = HID; W1_ = WoutC; W2_ = WoutC; A2_ = A1_;
    kstart = kz*256; nch = 4;
  } else {
    A1_ = sC + ((size_t)rp*3 + 2)*BH;
    K1 = HID; W1_ = WoutC; W2_ = WoutC; A2_ = A1_;
    kstart = kz*256; nch = 4;
  }

  // ---- GEMM ----
  f32x4 z4 = {0.f,0.f,0.f,0.f};
  f32x4 acc[4][4];
  #pragma unroll
  for (int a = 0; a < 4; ++a) { acc[a][0]=z4; acc[a][1]=z4; acc[a][2]=z4; acc[a][3]=z4; }
  mm_core<4,4,2,4>(smem, jt << 8, kstart, nch, A1_, K1, A2_, W1_, W2_, acc);

  // ---- slab store: pack row pairs into u32, sc0/sc1 ----
  {
    const int lane = tid & 63, wave = tid >> 6;
    const int wr = wave >> 2, wc = wave & 3;
    const int rb = (lane >> 4) << 2, cbl = lane & 15;
    unsigned* const sb = slabs + (size_t)bid * 16384;   // u32 units
    #pragma unroll
    for (int mi = 0; mi < 4; ++mi)
      #pragma unroll
      for (int ni = 0; ni < 4; ++ni) {
        const int row = (wr << 6) + (mi << 4) + rb;     // multiple of 4
        const int col = (wc << 6) + (ni << 4) + cbl;
        const unsigned p0 = (unsigned)f16_rne(acc[mi][ni][0])
                          | ((unsigned)f16_rne(acc[mi][ni][1]) << 16);
        const unsigned p1 = (unsigned)f16_rne(acc[mi][ni][2])
                          | ((unsigned)f16_rne(acc[mi][ni][3]) << 16);
        st1u(sb + ((row >> 1) << 8) + col, p0);
        st1u(sb + (((row >> 1) + 1) << 8) + col, p1);
      }
  }
  asm volatile("s_waitcnt vmcnt(0)" ::: "memory");
  __syncthreads();
  if (tid == 0) bump(&tk[gid*32]);
  if (role == 1) return;                 // ext: produce only

  // ---- spin: own group; gates l>=1 also ext group ----
  {
    if (tid == 0) {
      unsigned* a = &tk[gid*32];
      const int ta = KZ*(t+1);
      while ((int)ldcnt(a) - ta < 0) __builtin_amdgcn_s_sleep(2);
    } else if (tid == 1 && role == 0 && l) {
      unsigned* b = &tk[((l==1 ? 48 : 52) + (jt >> 2))*32];
      const int tb = 4*(t+1);
      while ((int)ldcnt(b) - tb < 0) __builtin_amdgcn_s_sleep(2);
    }
    __syncthreads();
  }

  // ---- reduce my 1/KZ m-shard ----
  const unsigned* gb = slabs + (size_t)(bid - kz) * 16384;
  if (role == 0) {
    const unsigned* eb = l ? slabs + (size_t)((l==1 ? 128 : 208) + ((jt >> 2) << 2)) * 16384
                           : nullptr;
    #pragma unroll
    for (int it = 0; it < 2; ++it) {
      const int u = it*512 + tid;            // 0..1023
      const int nl = u & 63, rpl = u >> 6;   // 0..15
      const int rpair = (kz << 4) + rpl;     // rowpair 0..63
      const int o = (rpair << 8) + (nl << 2);
      u32x4 a0 = ld4u(gb + o);
      u32x4 a1 = ld4u(gb + 16384 + o);
      u32x4 a2 = ld4u(gb + 32768 + o);
      u32x4 a3 = ld4u(gb + 49152 + o);
      unsigned e0 = 0, e1 = 0, e2 = 0, e3 = 0;
      const int n = (jt << 6) + nl;
      if (l) {
        const int oe = (rpair << 8) + (n & 255);
        e0 = ld1u(eb + oe);
        e1 = ld1u(eb + 16384 + oe);
        e2 = ld1u(eb + 32768 + oe);
        e3 = ld1u(eb + 49152 + oe);
      }
      wait0();
      float gate[4][2];
      #pragma unroll
      for (int g = 0; g < 4; ++g) {
        const unsigned v0 = a0[g], v1 = a1[g], v2 = a2[g], v3 = a3[g];
        gate[g][0] = f16_tof((unsigned short)(v0 & 0xffff)) + f16_tof((unsigned short)(v1 & 0xffff))
                   + f16_tof((unsigned short)(v2 & 0xffff)) + f16_tof((unsigned short)(v3 & 0xffff));
        gate[g][1] = f16_tof((unsigned short)(v0 >> 16)) + f16_tof((unsigned short)(v1 >> 16))
                   + f16_tof((unsigned short)(v2 >> 16)) + f16_tof((unsigned short)(v3 >> 16));
      }
      const float4 bp = ((const float4*)(bperm + (l << 12)))[n];
      float ftv[2] = {0.f, 0.f};
      if (l) {
        const float bo = bout[n];
        ftv[0] = bo + f16_tof((unsigned short)(e0 & 0xffff)) + f16_tof((unsigned short)(e1 & 0xffff))
                    + f16_tof((unsigned short)(e2 & 0xffff)) + f16_tof((unsigned short)(e3 & 0xffff));
        ftv[1] = bo + f16_tof((unsigned short)(e0 >> 16)) + f16_tof((unsigned short)(e1 >> 16))
                    + f16_tof((unsigned short)(e2 >> 16)) + f16_tof((unsigned short)(e3 >> 16));
      }
      #pragma unroll
      for (int j = 0; j < 2; ++j) {
        const int m = (rpair << 1) + j;
        const float gi_ = gate[0][j] + bp.x;
        const float gf_ = gate[1][j] + bp.y;
        const float gg_ = gate[2][j] + bp.z;
        const float go_ = gate[3][j] + bp.w;
        const size_t ci = (size_t)l*BH + (m << 10) + n;
        const float cn = sigf(gf_)*cst[ci] + sigf(gi_)*tanhf(gg_);
        cst[ci] = cn;
        const float h = sigf(go_)*tanhf(cn);
        const size_t wi = ((size_t)p*3 + l)*BH + (m << 10) + n;
        hC[wi] = f16_rne(h);
        sC[wi] = f16_rne(h + (l ? ftv[j] : 0.f));
      }
    }
  } else {
    float* const op = out + (size_t)t*BH;
    #pragma unroll
    for (int it = 0; it < 8; ++it) {
      const int u = it*512 + tid;            // 0..4095
      const int col = u & 255, rpl = u >> 8; // 0..15
      const int rpair = (kz << 4) + rpl;
      const int o = (rpair << 8) + col;
      const unsigned v0 = ld1u(gb + o);
      const unsigned v1 = ld1u(gb + 16384 + o);
      const unsigned v2 = ld1u(gb + 32768 + o);
      const unsigned v3 = ld1u(gb + 49152 + o);
      wait0();
      const int n = (jt << 8) + col;
      const float bo = bout[n];
      const float r0 = bo + f16_tof((unsigned short)(v0 & 0xffff)) + f16_tof((unsigned short)(v1 & 0xffff))
                         + f16_tof((unsigned short)(v2 & 0xffff)) + f16_tof((unsigned short)(v3 & 0xffff));
      const float r1 = bo + f16_tof((unsigned short)(v0 >> 16)) + f16_tof((unsigned short)(v1 >> 16))
                         + f16_tof((unsigned short)(v2 >> 16)) + f16_tof((unsigned short)(v3 >> 16));
      const int m = rpair << 1;
      op[((size_t)m << 10) + n] = r0;
      op[((size_t)(m+1) << 10) + n] = r1;
    }
  }
}

// ---------------- host ----------------

extern "C" void kernel_launch(void* const* d_in, const int* in_sizes, int n_in,
                              void* d_out, int out_size, void* d_ws, size_t ws_size,
                              hipStream_t stream) {
  const float* x    = (const float*)d_in[0];
  const float* Wih0 = (const float*)d_in[1];
  const float* Wihr = (const float*)d_in[2];
  const float* Whh  = (const float*)d_in[3];
  const float* bih  = (const float*)d_in[4];
  const float* bhh  = (const float*)d_in[5];
  const float* Wout = (const float*)d_in[6];
  const float* bout = (const float*)d_in[7];
  float* out = (float*)d_out;

  char* base = (char*)d_ws;
  size_t off = 0;
  auto alloc = [&](size_t bytes) -> char* {
    char* p = base + off;
    off = (off + bytes + 255) & ~(size_t)255;
    return p;
  };
  unsigned* tk = (unsigned*)alloc(64ull*32*4);                     // tickets first
  unsigned* slabs = (unsigned*)alloc(240ull*16384*4);              // 15.7 MB packed f16
  float* cst   = (float*)alloc(3ull*BH*4);
  float* bperm = (float*)alloc(3ull*G4*4);
  unsigned short* hC = (unsigned short*)alloc(2ull*3*BH*2);
  unsigned short* sC = (unsigned short*)alloc(2ull*3*BH*2);
  unsigned short* xC = (unsigned short*)alloc((size_t)SEQ*BATCH*FEAT*2);
  unsigned short* Wih0p = (unsigned short*)alloc((size_t)G4*FEAT*2);
  unsigned short* Whhp  = (unsigned short*)alloc(3ull*G4*HID*2);
  unsigned short* Wf1p  = (unsigned short*)alloc((size_t)G4*HID*2);
  unsigned short* Wf2p  = (unsigned short*)alloc((size_t)G4*HID*2);
  unsigned short* WoutC = (unsigned short*)alloc((size_t)HID*HID*2);
  unsigned short* WoutT = (unsigned short*)alloc((size_t)HID*HID*2);
  unsigned short* WrC   = (unsigned short*)alloc(2ull*G4*HID*2);   // staging

  // one-time conversions & folds
  conv16<<<2048, 256, 0, stream>>>(Wihr, WrC, 2*G4*HID/4);
  conv16<<<1024, 256, 0, stream>>>(Wout, WoutC, HID*HID/4);
  transp16<<<4096, 256, 0, stream>>>(Wout, WoutT);
  conv_perm16<<<2048, 256, 0, stream>>>(Wih0, Wih0p, G4*FEAT/4, 7);
  for (int l = 0; l < 3; ++l)
    conv_perm16<<<2048, 256, 0, stream>>>(Whh + (size_t)l*G4*HID,
        Whhp + (size_t)l*G4*HID, G4*HID/4, 8);
  conv16<<<2048, 256, 0, stream>>>(x, xC, SEQ*BATCH*FEAT/4);
  wfuse_kernel<<<dim3(32,4), 512, 0, stream>>>(WrC,                  WoutT, Wf1p);
  wfuse_kernel<<<dim3(32,4), 512, 0, stream>>>(WrC + (size_t)G4*HID, WoutT, Wf2p);
  bias_perm<<<48, 256, 0, stream>>>(bih, bhh, bperm);
  gemvf<<<16, 256, 0, stream>>>(Wihr,                  bout, bperm + G4,   G4);
  gemvf<<<16, 256, 0, stream>>>(Wihr + (size_t)G4*HID, bout, bperm + 2*G4, G4);

  // zero recurrent state + tickets each call (replayed in graph)
  hipMemsetAsync(cst, 0, 3ull*BH*4, stream);
  hipMemsetAsync(hC, 0, 2ull*3*BH*2, stream);
  hipMemsetAsync(tk, 0, 64ull*32*4, stream);

  for (int d = 0; d < SEQ + 3; ++d) {
    diag_fused<<<240, 512, 0, stream>>>(d, xC, hC, sC,
        Wih0p, Whhp, Wf1p, Wf2p, WoutC, bperm, bout, cst, slabs, tk, out);
  }
}

// Round 18
// 4667.652 us; speedup vs baseline: 1.0414x; 1.0414x over previous
//
#include <hip/hip_runtime.h>
#include <cmath>

#define SEQ  256
#define BATCH 128
#define FEAT 512
#define HID  1024
#define G4   4096
#define BH (BATCH*HID)

typedef __attribute__((ext_vector_type(8))) _Float16 f16x8;
typedef __attribute__((ext_vector_type(4))) float f32x4;
typedef __attribute__((ext_vector_type(4))) unsigned u32x4;

__device__ __forceinline__ unsigned short f16_rne(float f) {
  _Float16 h = (_Float16)f;
  return __builtin_bit_cast(unsigned short, h);
}
__device__ __forceinline__ float f16_tof(unsigned short s) {
  return (float)__builtin_bit_cast(_Float16, s);
}
__device__ __forceinline__ void gload16(const unsigned short* g, unsigned short* l) {
  __builtin_amdgcn_global_load_lds(
      (const __attribute__((address_space(1))) unsigned int*)g,
      (__attribute__((address_space(3))) unsigned int*)l, 16, 0, 0);
}
__device__ __forceinline__ float sigf(float x) { return 1.f/(1.f+expf(-x)); }

// ---- sc0/sc1 (L3-coherence-point) slab primitives — R10-validated ----
__device__ __forceinline__ void st1u(unsigned* p, unsigned v) {
  asm volatile("global_store_dword %0, %1, off sc0 sc1" :: "v"(p), "v"(v) : "memory");
}
__device__ __forceinline__ u32x4 ld4u(const unsigned* p) {
  u32x4 r;
  asm volatile("global_load_dwordx4 %0, %1, off sc0 sc1" : "=v"(r) : "v"(p) : "memory");
  return r;
}
__device__ __forceinline__ unsigned ld1u(const unsigned* p) {
  unsigned r;
  asm volatile("global_load_dword %0, %1, off sc0 sc1" : "=v"(r) : "v"(p) : "memory");
  return r;
}
__device__ __forceinline__ void wait0() {
  asm volatile("s_waitcnt vmcnt(0)" ::: "memory");
  __builtin_amdgcn_sched_barrier(0);      // rule #18
}
__device__ __forceinline__ unsigned ldcnt(unsigned* p) {
  return __hip_atomic_load(p, __ATOMIC_RELAXED, __HIP_MEMORY_SCOPE_SYSTEM);
}
__device__ __forceinline__ void bump(unsigned* p) {
  __hip_atomic_fetch_add(p, 1u, __ATOMIC_RELAXED, __HIP_MEMORY_SCOPE_SYSTEM);
}

// ---------------- one-time conversion kernels ----------------

__global__ __launch_bounds__(256)
void conv16(const float* __restrict__ src, unsigned short* __restrict__ dst, int n4) {
  for (int i = blockIdx.x*256 + threadIdx.x; i < n4; i += gridDim.x*256) {
    const float4 v = ((const float4*)src)[i];
    ushort4 h;
    h.x = f16_rne(v.x); h.y = f16_rne(v.y); h.z = f16_rne(v.z); h.w = f16_rne(v.w);
    ((ushort4*)dst)[i] = h;
  }
}

// WoutT[c][k] = f16(Wout[k][c])
__global__ __launch_bounds__(256)
void transp16(const float* __restrict__ src, unsigned short* __restrict__ dst) {
  const int i = blockIdx.x*256 + threadIdx.x;   // 1M
  const int k = i >> 10, c = i & 1023;
  dst[(c << 10) + k] = f16_rne(src[i]);
}

// f32 -> f16 with gate-row permutation: r = g*1024+n -> prow = n*4+g
__global__ __launch_bounds__(256)
void conv_perm16(const float* __restrict__ src, unsigned short* __restrict__ dst,
                 int n4, int ksh) {
  for (int i = blockIdx.x*256 + threadIdx.x; i < n4; i += gridDim.x*256) {
    const float4 v = ((const float4*)src)[i];
    const int row = i >> ksh, cq = i & ((1 << ksh) - 1);
    const int prow = ((row & 1023) << 2) | (row >> 10);
    ushort4 h;
    h.x = f16_rne(v.x); h.y = f16_rne(v.y); h.z = f16_rne(v.z); h.w = f16_rne(v.w);
    ((ushort4*)dst)[(prow << ksh) + cq] = h;
  }
}

// bperm[l][prow] = bih + bhh (gate-permuted, f32)
__global__ __launch_bounds__(256)
void bias_perm(const float* __restrict__ bih, const float* __restrict__ bhh,
               float* __restrict__ bperm) {
  const int i = blockIdx.x*256 + threadIdx.x;
  if (i >= 3*G4) return;
  const int l = i >> 12, r = i & 4095;
  const int prow = ((r & 1023) << 2) | (r >> 10);
  bperm[(l << 12) + prow] = bih[i] + bhh[i];
}

// dst[prow(r)] += W[r,:] . b   (f32 weights, gate-permuted dest)
__global__ __launch_bounds__(256)
void gemvf(const float* __restrict__ W, const float* __restrict__ b,
           float* __restrict__ dst, int nrows) {
  const int r = blockIdx.x*256 + threadIdx.x;
  if (r >= nrows) return;
  const float4* wr = (const float4*)(W + (size_t)r*HID);
  float acc = 0.f;
  for (int k = 0; k < 256; ++k) {
    const float4 w = wr[k]; const float4 bb = ((const float4*)b)[k];
    acc += w.x*bb.x + w.y*bb.y + w.z*bb.z + w.w*bb.w;
  }
  dst[((r & 1023) << 2) | (r >> 10)] += acc;
}

// ---------------- 1-product fp16 MFMA GEMM core (R15/R16-verified) ----------------
// acc += A @ W^T. 8 waves as WRN x WCN; wave tile (MI*16)x(NI*16);
// BM=128, BN=256, BK=64. Double-buffered LDS + gload_lds(16B) + XOR swizzle.
template<int MI, int NI, int WRN, int WCN>
__device__ __forceinline__ void mm_core(
    unsigned short* lds, int n0, int kstart, int nch,
    const unsigned short* A1, int K1, const unsigned short* A2,
    const unsigned short* W1, const unsigned short* W2,
    f32x4 acc[MI][NI])
{
  constexpr int AROWS = WRN*MI*16;          // 128
  constexpr int WROWS = WCN*NI*16;          // 256
  constexpr int OW  = AROWS*64;
  constexpr int STRIDE = (AROWS + WROWS)*64;
  constexpr int NLD = (AROWS + WROWS)/64;   // 6
  const int tid = threadIdx.x;
  const int lane = tid & 63, wave = tid >> 6;
  const int wr = wave / WCN, wc = wave % WCN;
  const int rl = lane >> 3, cc = lane & 7;
  const int gcol = (cc ^ rl) << 3;

  auto stage = [&](int ch) {
    const int kg = kstart + (ch << 6);
    const unsigned short *pA, *pW; int sA, sW;
    if (kg < K1) { pA = A1 + kg; sA = K1;   pW = W1 + kg; sW = K1; }
    else { const int k2 = kg - K1; pA = A2 + k2; sA = 1024; pW = W2 + k2; sW = 1024; }
    unsigned short* const db = lds + (ch & 1)*STRIDE;
    #pragma unroll
    for (int q = 0; q < NLD; ++q) {
      const int g = wave*NLD + q;
      if (g < AROWS/8)
        gload16(pA + (size_t)(g*8 + rl)*sA + gcol, db + g*512);
      else
        gload16(pW + (size_t)(n0 + (g - AROWS/8)*8 + rl)*sW + gcol, db + g*512);
    }
  };

  stage(0);
  for (int ch = 0; ch < nch; ++ch) {
    if (ch + 1 < nch) {
      stage(ch + 1);
      asm volatile("s_waitcnt vmcnt(6)" ::: "memory");
    } else {
      asm volatile("s_waitcnt vmcnt(0)" ::: "memory");
    }
    __builtin_amdgcn_sched_barrier(0);
    __builtin_amdgcn_s_barrier();
    const unsigned short* const cb = lds + (ch & 1)*STRIDE;
    #pragma unroll
    for (int kh = 0; kh < 2; ++kh) {
      const int j0 = (kh << 2) + (lane >> 4);
      f16x8 ah[MI], bh[NI];
      #pragma unroll
      for (int mi = 0; mi < MI; ++mi) {
        const int row = wr*(MI*16) + (mi << 4) + (lane & 15);
        const int off = row*64 + ((j0 ^ (row & 7)) << 3);
        ah[mi] = *(const f16x8*)(cb + off);
      }
      #pragma unroll
      for (int ni = 0; ni < NI; ++ni) {
        const int wrow = wc*(NI*16) + (ni << 4) + (lane & 15);
        const int off = wrow*64 + ((j0 ^ (wrow & 7)) << 3);
        bh[ni] = *(const f16x8*)(cb + OW + off);
      }
      #pragma unroll
      for (int mi = 0; mi < MI; ++mi)
        #pragma unroll
        for (int ni = 0; ni < NI; ++ni)
          acc[mi][ni] = __builtin_amdgcn_mfma_f32_16x16x32_f16(ah[mi], bh[ni], acc[mi][ni], 0,0,0);
    }
    __builtin_amdgcn_s_barrier();
  }
}

// ---------------- Wfused = Wihr @ Wout -> gate-permuted f16 ----------------
__global__ __launch_bounds__(512, 2)
void wfuse_kernel(const unsigned short* __restrict__ A,
                  const unsigned short* __restrict__ WT,
                  unsigned short* __restrict__ dstP)
{
  __shared__ unsigned short smem[2*(128+256)*64];   // 96 KB
  const int mb = blockIdx.x, jy = blockIdx.y;
  const unsigned short* Ar = A + (size_t)(mb*128)*HID;
  f32x4 z4 = {0.f,0.f,0.f,0.f};
  f32x4 acc[4][4];
  #pragma unroll
  for (int a = 0; a < 4; ++a) { acc[a][0]=z4; acc[a][1]=z4; acc[a][2]=z4; acc[a][3]=z4; }
  mm_core<4,4,2,4>(smem, jy << 8, 0, 16, Ar, HID, Ar, WT, WT, acc);

  const int lane = threadIdx.x & 63, wave = threadIdx.x >> 6;
  const int wr = wave >> 2, wc = wave & 3;
  const int rb = (lane >> 4) << 2, cbl = lane & 15;
  #pragma unroll
  for (int mi = 0; mi < 4; ++mi)
    #pragma unroll
    for (int ni = 0; ni < 4; ++ni)
      #pragma unroll
      for (int r = 0; r < 4; ++r) {
        const int row = mb*128 + (wr << 6) + (mi << 4) + rb + r;
        const int col = (jy << 8) + (wc << 6) + (ni << 4) + cbl;
        dstP[((size_t)(((row & 1023) << 2) | (row >> 10)) << 10) + col] = f16_rne(acc[mi][ni][r]);
      }
}

// ---------------- fused per-diagonal kernel (ONE launch per diag) ----------------
// 240 blocks, 96KB LDS -> 1/CU, all co-resident:
//   [0,64)    gates l=0 (jt 0..15, kz 0..3)  K=1536 = x | h0          (6 chunks)
//   [64,128)  gates l=1                      K=2048 = s0 | h1         (8 chunks)
//   [128,144) ext  l=1 (jtf 0..3, kz 0..3)   K=1024 = s0 @ Wout       (4 chunks)
//   [144,208) gates l=2                      K=2048 = s1 | h2         (8 chunks)
//   [208,224) ext  l=2                       K=1024 = s1 @ Wout       (4 chunks)
//   [224,240) out  (jt 0..3, kz 0..3)        K=1024 = s2 @ Wout       (4 chunks)
// Slabs: f16 row-pair-packed u32, sc0/sc1 both sides; relaxed system tickets.
__global__ __launch_bounds__(512, 1)
void diag_fused(int d,
    const unsigned short* __restrict__ xC,
    unsigned short* __restrict__ hC,   // [2][3][BH]
    unsigned short* __restrict__ sC,   // [2][3][BH]
    const unsigned short* __restrict__ Wih0p, const unsigned short* __restrict__ Whhp,
    const unsigned short* __restrict__ Wf1p,  const unsigned short* __restrict__ Wf2p,
    const unsigned short* __restrict__ WoutC,
    const float* __restrict__ bperm, const float* __restrict__ bout,
    float* __restrict__ cst, unsigned* __restrict__ slabs,
    unsigned* __restrict__ tk, float* __restrict__ out)
{
  __shared__ unsigned short smem[2*(128+256)*64];   // 96 KB
  const int bid = blockIdx.x, tid = threadIdx.x;
  const int p = d & 1, rp = 1 - p;                  // write slot p, read slot rp

  int l, jt, kz, KZ, gid, role;                     // role 0=gates 1=ext 2=out
  if (bid < 64)       { l=0; jt=bid>>2;            kz=bid&3; KZ=4; gid=jt;    role=0; }
  else if (bid < 128) { l=1; int u=bid-64;  jt=u>>2; kz=u&3; KZ=4; gid=16+jt; role=0; }
  else if (bid < 144) { l=1; int w=bid-128; jt=w>>2; kz=w&3; KZ=4; gid=48+jt; role=1; }
  else if (bid < 208) { l=2; int u=bid-144; jt=u>>2; kz=u&3; KZ=4; gid=32+jt; role=0; }
  else if (bid < 224) { l=2; int w=bid-208; jt=w>>2; kz=w&3; KZ=4; gid=52+jt; role=1; }
  else                { l=3; int u=bid-224; jt=u>>2; kz=u&3; KZ=4; gid=56+jt; role=2; }
  const int t = d - ((role==2) ? 3 : l);
  if (t < 0 || t >= SEQ) return;

  // ---- operand selection ----
  const unsigned short *A1_, *A2_, *W1_, *W2_;
  int K1, kstart, nch;
  if (role == 0) {
    if (l == 0) {
      A1_ = xC + (size_t)t*BATCH*FEAT;
      K1 = FEAT; W1_ = Wih0p; kstart = kz*384; nch = 6;
    } else {
      A1_ = sC + ((size_t)rp*3 + (l-1))*BH;
      K1 = HID; W1_ = (l==1) ? Wf1p : Wf2p; kstart = kz*512; nch = 8;
    }
    A2_ = hC + ((size_t)rp*3 + l)*BH;
    W2_ = Whhp + (size_t)l*G4*HID;
  } else if (role == 1) {
    A1_ = sC + ((size_t)rp*3 + (l-1))*BH;
    K1 = HID; W1_ = WoutC; W2_ = WoutC; A2_ = A1_;
    kstart = kz*256; nch = 4;
  } else {
    A1_ = sC + ((size_t)rp*3 + 2)*BH;
    K1 = HID; W1_ = WoutC; W2_ = WoutC; A2_ = A1_;
    kstart = kz*256; nch = 4;
  }

  // ---- GEMM ----
  f32x4 z4 = {0.f,0.f,0.f,0.f};
  f32x4 acc[4][4];
  #pragma unroll
  for (int a = 0; a < 4; ++a) { acc[a][0]=z4; acc[a][1]=z4; acc[a][2]=z4; acc[a][3]=z4; }
  mm_core<4,4,2,4>(smem, jt << 8, kstart, nch, A1_, K1, A2_, W1_, W2_, acc);

  // ---- slab store: pack row pairs into u32, sc0/sc1 ----
  {
    const int lane = tid & 63, wave = tid >> 6;
    const int wr = wave >> 2, wc = wave & 3;
    const int rb = (lane >> 4) << 2, cbl = lane & 15;
    unsigned* const sb = slabs + (size_t)bid * 16384;   // u32 units
    #pragma unroll
    for (int mi = 0; mi < 4; ++mi)
      #pragma unroll
      for (int ni = 0; ni < 4; ++ni) {
        const int row = (wr << 6) + (mi << 4) + rb;     // multiple of 4
        const int col = (wc << 6) + (ni << 4) + cbl;
        const unsigned p0 = (unsigned)f16_rne(acc[mi][ni][0])
                          | ((unsigned)f16_rne(acc[mi][ni][1]) << 16);
        const unsigned p1 = (unsigned)f16_rne(acc[mi][ni][2])
                          | ((unsigned)f16_rne(acc[mi][ni][3]) << 16);
        st1u(sb + ((row >> 1) << 8) + col, p0);
        st1u(sb + (((row >> 1) + 1) << 8) + col, p1);
      }
  }
  asm volatile("s_waitcnt vmcnt(0)" ::: "memory");
  __syncthreads();
  if (tid == 0) bump(&tk[gid*32]);
  if (role == 1) return;                 // ext: produce only

  // ---- spin: own group; gates l>=1 also ext group ----
  {
    if (tid == 0) {
      unsigned* a = &tk[gid*32];
      const int ta = KZ*(t+1);
      while ((int)ldcnt(a) - ta < 0) __builtin_amdgcn_s_sleep(2);
    } else if (tid == 1 && role == 0 && l) {
      unsigned* b = &tk[((l==1 ? 48 : 52) + (jt >> 2))*32];
      const int tb = 4*(t+1);
      while ((int)ldcnt(b) - tb < 0) __builtin_amdgcn_s_sleep(2);
    }
    __syncthreads();
  }

  // ---- reduce my 1/KZ m-shard ----
  const unsigned* gb = slabs + (size_t)(bid - kz) * 16384;
  if (role == 0) {
    const unsigned* eb = l ? slabs + (size_t)((l==1 ? 128 : 208) + ((jt >> 2) << 2)) * 16384
                           : nullptr;
    #pragma unroll
    for (int it = 0; it < 2; ++it) {
      const int u = it*512 + tid;            // 0..1023
      const int nl = u & 63, rpl = u >> 6;   // 0..15
      const int rpair = (kz << 4) + rpl;     // rowpair 0..63
      const int o = (rpair << 8) + (nl << 2);
      u32x4 a0 = ld4u(gb + o);
      u32x4 a1 = ld4u(gb + 16384 + o);
      u32x4 a2 = ld4u(gb + 32768 + o);
      u32x4 a3 = ld4u(gb + 49152 + o);
      unsigned e0 = 0, e1 = 0, e2 = 0, e3 = 0;
      const int n = (jt << 6) + nl;
      if (l) {
        const int oe = (rpair << 8) + (n & 255);
        e0 = ld1u(eb + oe);
        e1 = ld1u(eb + 16384 + oe);
        e2 = ld1u(eb + 32768 + oe);
        e3 = ld1u(eb + 49152 + oe);
      }
      wait0();
      float gate[4][2];
      #pragma unroll
      for (int g = 0; g < 4; ++g) {
        const unsigned v0 = a0[g], v1 = a1[g], v2 = a2[g], v3 = a3[g];
        gate[g][0] = f16_tof((unsigned short)(v0 & 0xffff)) + f16_tof((unsigned short)(v1 & 0xffff))
                   + f16_tof((unsigned short)(v2 & 0xffff)) + f16_tof((unsigned short)(v3 & 0xffff));
        gate[g][1] = f16_tof((unsigned short)(v0 >> 16)) + f16_tof((unsigned short)(v1 >> 16))
                   + f16_tof((unsigned short)(v2 >> 16)) + f16_tof((unsigned short)(v3 >> 16));
      }
      const float4 bp = ((const float4*)(bperm + (l << 12)))[n];
      float ftv[2] = {0.f, 0.f};
      if (l) {
        const float bo = bout[n];
        ftv[0] = bo + f16_tof((unsigned short)(e0 & 0xffff)) + f16_tof((unsigned short)(e1 & 0xffff))
                    + f16_tof((unsigned short)(e2 & 0xffff)) + f16_tof((unsigned short)(e3 & 0xffff));
        ftv[1] = bo + f16_tof((unsigned short)(e0 >> 16)) + f16_tof((unsigned short)(e1 >> 16))
                    + f16_tof((unsigned short)(e2 >> 16)) + f16_tof((unsigned short)(e3 >> 16));
      }
      #pragma unroll
      for (int j = 0; j < 2; ++j) {
        const int m = (rpair << 1) + j;
        const float gi_ = gate[0][j] + bp.x;
        const float gf_ = gate[1][j] + bp.y;
        const float gg_ = gate[2][j] + bp.z;
        const float go_ = gate[3][j] + bp.w;
        const size_t ci = (size_t)l*BH + (m << 10) + n;
        const float cn = sigf(gf_)*cst[ci] + sigf(gi_)*tanhf(gg_);
        cst[ci] = cn;
        const float h = sigf(go_)*tanhf(cn);
        const size_t wi = ((size_t)p*3 + l)*BH + (m << 10) + n;
        hC[wi] = f16_rne(h);
        sC[wi] = f16_rne(h + (l ? ftv[j] : 0.f));
      }
    }
  } else {
    float* const op = out + (size_t)t*BH;
    #pragma unroll
    for (int it = 0; it < 8; ++it) {
      const int u = it*512 + tid;            // 0..4095
      const int col = u & 255, rpl = u >> 8; // 0..15
      const int rpair = (kz << 4) + rpl;
      const int o = (rpair << 8) + col;
      const unsigned v0 = ld1u(gb + o);
      const unsigned v1 = ld1u(gb + 16384 + o);
      const unsigned v2 = ld1u(gb + 32768 + o);
      const unsigned v3 = ld1u(gb + 49152 + o);
      wait0();
      const int n = (jt << 8) + col;
      const float bo = bout[n];
      const float r0 = bo + f16_tof((unsigned short)(v0 & 0xffff)) + f16_tof((unsigned short)(v1 & 0xffff))
                         + f16_tof((unsigned short)(v2 & 0xffff)) + f16_tof((unsigned short)(v3 & 0xffff));
      const float r1 = bo + f16_tof((unsigned short)(v0 >> 16)) + f16_tof((unsigned short)(v1 >> 16))
                         + f16_tof((unsigned short)(v2 >> 16)) + f16_tof((unsigned short)(v3 >> 16));
      const int m = rpair << 1;
      op[((size_t)m << 10) + n] = r0;
      op[((size_t)(m+1) << 10) + n] = r1;
    }
  }
}

// ---------------- host ----------------

extern "C" void kernel_launch(void* const* d_in, const int* in_sizes, int n_in,
                              void* d_out, int out_size, void* d_ws, size_t ws_size,
                              hipStream_t stream) {
  const float* x    = (const float*)d_in[0];
  const float* Wih0 = (const float*)d_in[1];
  const float* Wihr = (const float*)d_in[2];
  const float* Whh  = (const float*)d_in[3];
  const float* bih  = (const float*)d_in[4];
  const float* bhh  = (const float*)d_in[5];
  const float* Wout = (const float*)d_in[6];
  const float* bout = (const float*)d_in[7];
  float* out = (float*)d_out;

  char* base = (char*)d_ws;
  size_t off = 0;
  auto alloc = [&](size_t bytes) -> char* {
    char* p = base + off;
    off = (off + bytes + 255) & ~(size_t)255;
    return p;
  };
  unsigned* tk = (unsigned*)alloc(64ull*32*4);                     // tickets first
  unsigned* slabs = (unsigned*)alloc(240ull*16384*4);              // 15.7 MB packed f16
  float* cst   = (float*)alloc(3ull*BH*4);
  float* bperm = (float*)alloc(3ull*G4*4);
  unsigned short* hC = (unsigned short*)alloc(2ull*3*BH*2);
  unsigned short* sC = (unsigned short*)alloc(2ull*3*BH*2);
  unsigned short* xC = (unsigned short*)alloc((size_t)SEQ*BATCH*FEAT*2);
  unsigned short* Wih0p = (unsigned short*)alloc((size_t)G4*FEAT*2);
  unsigned short* Whhp  = (unsigned short*)alloc(3ull*G4*HID*2);
  unsigned short* Wf1p  = (unsigned short*)alloc((size_t)G4*HID*2);
  unsigned short* Wf2p  = (unsigned short*)alloc((size_t)G4*HID*2);
  unsigned short* WoutC = (unsigned short*)alloc((size_t)HID*HID*2);
  unsigned short* WoutT = (unsigned short*)alloc((size_t)HID*HID*2);
  unsigned short* WrC   = (unsigned short*)alloc(2ull*G4*HID*2);   // staging

  // one-time conversions & folds
  conv16<<<2048, 256, 0, stream>>>(Wihr, WrC, 2*G4*HID/4);
  conv16<<<1024, 256, 0, stream>>>(Wout, WoutC, HID*HID/4);
  transp16<<<4096, 256, 0, stream>>>(Wout, WoutT);
  conv_perm16<<<2048, 256, 0, stream>>>(Wih0, Wih0p, G4*FEAT/4, 7);
  for (int l = 0; l < 3; ++l)
    conv_perm16<<<2048, 256, 0, stream>>>(Whh + (size_t)l*G4*HID,
        Whhp + (size_t)l*G4*HID, G4*HID/4, 8);
  conv16<<<2048, 256, 0, stream>>>(x, xC, SEQ*BATCH*FEAT/4);
  wfuse_kernel<<<dim3(32,4), 512, 0, stream>>>(WrC,                  WoutT, Wf1p);
  wfuse_kernel<<<dim3(32,4), 512, 0, stream>>>(WrC + (size_t)G4*HID, WoutT, Wf2p);
  bias_perm<<<48, 256, 0, stream>>>(bih, bhh, bperm);
  gemvf<<<16, 256, 0, stream>>>(Wihr,                  bout, bperm + G4,   G4);
  gemvf<<<16, 256, 0, stream>>>(Wihr + (size_t)G4*HID, bout, bperm + 2*G4, G4);

  // zero recurrent state + tickets each call (replayed in graph)
  hipMemsetAsync(cst, 0, 3ull*BH*4, stream);
  hipMemsetAsync(hC, 0, 2ull*3*BH*2, stream);
  hipMemsetAsync(tk, 0, 64ull*32*4, stream);

  for (int d = 0; d < SEQ + 3; ++d) {
    diag_fused<<<240, 512, 0, stream>>>(d, xC, hC, sC,
        Wih0p, Whhp, Wf1p, Wf2p, WoutC, bperm, bout, cst, slabs, tk, out);
  }
}